// Round 6
// baseline (83.203 us; speedup 1.0000x reference)
//
#include <hip/hip_runtime.h>
#include <math.h>

#define DIM 4096
#define BATCH 64

typedef __attribute__((ext_vector_type(8))) short short8;
typedef __attribute__((ext_vector_type(4))) float f32x4;
typedef __attribute__((ext_vector_type(4))) unsigned int u32x4;

__device__ __forceinline__ float4 ld4(const float* p) {
    return *reinterpret_cast<const float4*>(p);
}

// f32 -> bf16 bits, round-to-nearest-even
__device__ __forceinline__ unsigned short f2bf(float f) {
    unsigned u = __builtin_bit_cast(unsigned, f);
    u = (u + 0x7fffu + ((u >> 16) & 1u)) >> 16;
    return (unsigned short)u;
}

// pack two f32 -> one u32 of two bf16 (truncation; cheap)
__device__ __forceinline__ unsigned pack_bf2(float x, float y) {
    return (__builtin_bit_cast(unsigned, x) >> 16) |
           (__builtin_bit_cast(unsigned, y) & 0xffff0000u);
}

// K1: L2-normalize rows of input_x; emit bf16 in MFMA fragment orders.
//   MFMA 16x16x32 bf16 (verified, learn_hip m89):
//     A: lane l, reg j -> A[l&15][(l>>4)*8 + j]
//     B: lane l, reg j -> B[(l>>4)*8 + j][l&15]
//     D: lane l, reg q -> D[(l>>4)*4 + q][l&15]
// xb1: B-frags for y = W @ xnT: K-dim = k, col = b.   [bt(4)][kstep(128)][lane] x short8
// xa2: A-frags for d^T = xa2 @ (NC*y^T): A[j][b] = xn[b][jcol]. [jt(256)][ks(2)][lane] x short8
__global__ __launch_bounds__(256) void k_norm(const float* __restrict__ x,
                                              unsigned short* __restrict__ xb1,
                                              unsigned short* __restrict__ xa2) {
    const int b = blockIdx.x;
    const int tid = threadIdx.x;
    const float* row = x + (size_t)b * DIM;

    float ss = 0.f;
    for (int k = tid * 4; k < DIM; k += 256 * 4) {
        float4 v = ld4(row + k);
        ss += v.x * v.x + v.y * v.y + v.z * v.z + v.w * v.w;
    }
#pragma unroll
    for (int m = 32; m >= 1; m >>= 1) ss += __shfl_xor(ss, m, 64);

    __shared__ float wsum[4];
    if ((tid & 63) == 0) wsum[tid >> 6] = ss;
    __syncthreads();
    const float total = wsum[0] + wsum[1] + wsum[2] + wsum[3];
    const float scale = 1.0f / (sqrtf(total) + 1e-8f);

    const int bt = b >> 4;            // xb1 b-tile
    const int li = b & 15;            // xb1 col-in-tile
    const int ks  = b >> 5;           // xa2 K-step (0/1)
    const int bhi = (b >> 3) & 3;     // xa2 lane-high bits
    const int br  = b & 7;            // xa2 reg index

    for (int k = tid; k < DIM; k += 256) {
        const float v = row[k] * scale;
        const unsigned short h = f2bf(v);
        const int l1 = li | (((k & 31) >> 3) << 4);
        xb1[(size_t)((((bt * 128) + (k >> 5)) * 64 + l1) << 3) + (k & 7)] = h;
        const int l2 = (k & 15) | (bhi << 4);
        xa2[(size_t)(((((k >> 4) * 2) + ks) * 64 + l2) << 3) + br] = h;
    }
}

// K2: ypart[kc] = W[rt*16 .. +16, kc*1024 .. +1024] @ xnT-chunk
// grid (256, 4) x 256 thr. All 16 W float4 loads preissued -> deep MLP.
__global__ __launch_bounds__(256, 4) void k_wxt(const float* __restrict__ W,
                                                const unsigned short* __restrict__ xb1,
                                                float* __restrict__ ypart) {
    __shared__ f32x4 yp[4][4][64];   // [wave][bt][lane], 16 KB

    const int tid = threadIdx.x;
    const int w = tid >> 6;
    const int l = tid & 63;
    const int lr = l & 15;
    const int lh = l >> 4;
    const int rt = blockIdx.x;
    const int kc = blockIdx.y;
    const int i0 = rt * 16;

    // preload 8 K-steps of W (16 float4, 64 VGPR) — all in flight at once
    float4 wa[8], wb[8];
    const float* wp0 = W + (size_t)(i0 + lr) * DIM + (kc * 32 + w * 8) * 32 + lh * 8;
#pragma unroll
    for (int s = 0; s < 8; ++s) {
        wa[s] = ld4(wp0 + s * 32);
        wb[s] = ld4(wp0 + s * 32 + 4);
    }

    f32x4 acc0 = {0.f, 0.f, 0.f, 0.f};
    f32x4 acc1 = acc0, acc2 = acc0, acc3 = acc0;
    const short8* xb1v = (const short8*)xb1;

#pragma unroll
    for (int s = 0; s < 8; ++s) {
        const int kbg = kc * 32 + w * 8 + s;
        const int bs = kbg * 64 + l;
        const short8 b0 = xb1v[bs];
        const short8 b1 = xb1v[bs + 8192];
        const short8 b2 = xb1v[bs + 16384];
        const short8 b3 = xb1v[bs + 24576];
        u32x4 ap;
        ap[0] = pack_bf2(wa[s].x, wa[s].y);
        ap[1] = pack_bf2(wa[s].z, wa[s].w);
        ap[2] = pack_bf2(wb[s].x, wb[s].y);
        ap[3] = pack_bf2(wb[s].z, wb[s].w);
        const short8 a = __builtin_bit_cast(short8, ap);
        acc0 = __builtin_amdgcn_mfma_f32_16x16x32_bf16(a, b0, acc0, 0, 0, 0);
        acc1 = __builtin_amdgcn_mfma_f32_16x16x32_bf16(a, b1, acc1, 0, 0, 0);
        acc2 = __builtin_amdgcn_mfma_f32_16x16x32_bf16(a, b2, acc2, 0, 0, 0);
        acc3 = __builtin_amdgcn_mfma_f32_16x16x32_bf16(a, b3, acc3, 0, 0, 0);
    }
    yp[w][0][l] = acc0;
    yp[w][1][l] = acc1;
    yp[w][2][l] = acc2;
    yp[w][3][l] = acc3;
    __syncthreads();

    // reduce 4 wave-partials; thread t owns b = t&63, rows (t>>6)*4 .. +4
    {
        const int bb = tid & 63;
        const int btt = bb >> 4;
        const int rb = tid >> 6;
#pragma unroll
        for (int q = 0; q < 4; ++q) {
            const int r = rb * 4 + q;
            const int lii = (bb & 15) | ((r >> 2) << 4);
            const int jq = r & 3;
            float s = yp[0][btt][lii][jq] + yp[1][btt][lii][jq]
                    + yp[2][btt][lii][jq] + yp[3][btt][lii][jq];
            ypart[((size_t)kc * DIM + (i0 + r)) * 64 + bb] = s;
        }
    }
}

// K2b: reduce 4 K-partials; emit phase-2 B-fragments yab = bf16(NC * y^T)
//   per (rt, l): yab[(rt*64+l)*2 + h][j] = f2bf(NC * y[rt*16 + (l&15)][h*32 + (l>>4)*8 + j])
__global__ __launch_bounds__(256) void k_yfrag(const float* __restrict__ ypart,
                                               unsigned short* __restrict__ yab) {
    const int gid = blockIdx.x * 256 + threadIdx.x;   // 0 .. 16383
    const int rt = gid >> 6;
    const int l = gid & 63;
    const int lr = l & 15;
    const int lh = l >> 4;
    const float NC = -0.01f / 64.0f;
    short8* yabv = (short8*)yab;

#pragma unroll
    for (int h = 0; h < 2; ++h) {
        float s[8] = {};
#pragma unroll
        for (int kc = 0; kc < 4; ++kc) {
            const float* p = ypart + ((size_t)kc * DIM + (rt * 16 + lr)) * 64 + h * 32 + lh * 8;
            const float4 f0 = ld4(p);
            const float4 f1 = ld4(p + 4);
            s[0] += f0.x; s[1] += f0.y; s[2] += f0.z; s[3] += f0.w;
            s[4] += f1.x; s[5] += f1.y; s[6] += f1.z; s[7] += f1.w;
        }
        short8 fr;
#pragma unroll
        for (int j = 0; j < 8; ++j) fr[j] = (short)f2bf(NC * s[j]);
        yabv[(size_t)(rt * 64 + l) * 2 + h] = fr;
    }
}

// K3: out = W - lr*G + d, d^T-tiles = xa2 @ yab. No LDS, no barriers; 8-deep
// W/G register batching -> 16 HBM loads in flight per wave. grid (256,4) x 256.
__global__ __launch_bounds__(256, 4) void k_update(const float* __restrict__ W,
                                                   const float* __restrict__ G,
                                                   const unsigned short* __restrict__ xa2,
                                                   const unsigned short* __restrict__ yab,
                                                   float* __restrict__ out) {
    const int tid = threadIdx.x;
    const int wv = tid >> 6;
    const int l = tid & 63;
    const int lr = l & 15;
    const int lh = l >> 4;
    const int rt = blockIdx.x;
    const int cc = blockIdx.y;
    const int i0 = rt * 16;

    const short8* yabv = (const short8*)yab;
    const short8* xa2v = (const short8*)xa2;
    const short8 ya0 = yabv[(size_t)(rt * 64 + l) * 2];
    const short8 ya1 = yabv[(size_t)(rt * 64 + l) * 2 + 1];

    const size_t rowoff = (size_t)(i0 + lr) * DIM;
    const int jt0 = cc * 64 + wv * 16;
    constexpr float LRc = 0.001f;

    for (int t0 = 0; t0 < 16; t0 += 8) {
        float4 w8[8], g8[8];
#pragma unroll
        for (int i = 0; i < 8; ++i) {
            const size_t idx = rowoff + (jt0 + t0 + i) * 16 + lh * 4;
            w8[i] = ld4(W + idx);
            g8[i] = ld4(G + idx);
        }
#pragma unroll
        for (int i = 0; i < 8; ++i) {
            const int jt = jt0 + t0 + i;
            const short8 a0 = xa2v[(size_t)(jt * 2 + 0) * 64 + l];
            const short8 a1 = xa2v[(size_t)(jt * 2 + 1) * 64 + l];
            f32x4 d = {0.f, 0.f, 0.f, 0.f};
            d = __builtin_amdgcn_mfma_f32_16x16x32_bf16(a0, ya0, d, 0, 0, 0);
            d = __builtin_amdgcn_mfma_f32_16x16x32_bf16(a1, ya1, d, 0, 0, 0);
            const size_t idx = rowoff + jt * 16 + lh * 4;
            float4 o;
            o.x = w8[i].x - LRc * g8[i].x + d[0];
            o.y = w8[i].y - LRc * g8[i].y + d[1];
            o.z = w8[i].z - LRc * g8[i].z + d[2];
            o.w = w8[i].w - LRc * g8[i].w + d[3];
            *reinterpret_cast<float4*>(out + idx) = o;
        }
    }
}

extern "C" void kernel_launch(void* const* d_in, const int* in_sizes, int n_in,
                              void* d_out, int out_size, void* d_ws, size_t ws_size,
                              hipStream_t stream) {
    const float* W = (const float*)d_in[0];   // weight  (DIM x DIM)
    const float* X = (const float*)d_in[1];   // input_x (BATCH x DIM)
    const float* G = (const float*)d_in[2];   // grad    (DIM x DIM)
    float* out = (float*)d_out;

    unsigned short* xb1 = (unsigned short*)d_ws;                    // 512 KB
    unsigned short* xa2 = xb1 + (size_t)DIM * BATCH;                // 512 KB
    unsigned short* yab = xa2 + (size_t)DIM * BATCH;                // 512 KB
    float* ypart = (float*)(yab + (size_t)DIM * BATCH);             // 4 MB (4 x DIM x 64 f32)

    hipLaunchKernelGGL(k_norm, dim3(BATCH), dim3(256), 0, stream, X, xb1, xa2);
    hipLaunchKernelGGL(k_wxt, dim3(256, 4), dim3(256), 0, stream, W, xb1, ypart);
    hipLaunchKernelGGL(k_yfrag, dim3(64), dim3(256), 0, stream, ypart, yab);
    hipLaunchKernelGGL(k_update, dim3(256, 4), dim3(256), 0, stream,
                       W, G, xa2, yab, out);
}

// Round 7
// 73.463 us; speedup vs baseline: 1.1326x; 1.1326x over previous
//
#include <hip/hip_runtime.h>
#include <math.h>

#define DIM 4096
#define BATCH 64

typedef __attribute__((ext_vector_type(8))) short short8;
typedef __attribute__((ext_vector_type(4))) float f32x4;
typedef __attribute__((ext_vector_type(4))) unsigned int u32x4;

__device__ __forceinline__ float4 ld4(const float* p) {
    return *reinterpret_cast<const float4*>(p);
}

// f32 -> bf16 bits, round-to-nearest-even
__device__ __forceinline__ unsigned short f2bf(float f) {
    unsigned u = __builtin_bit_cast(unsigned, f);
    u = (u + 0x7fffu + ((u >> 16) & 1u)) >> 16;
    return (unsigned short)u;
}

// pack two f32 -> one u32 of two bf16 (truncation; cheap)
__device__ __forceinline__ unsigned pack_bf2(float x, float y) {
    return (__builtin_bit_cast(unsigned, x) >> 16) |
           (__builtin_bit_cast(unsigned, y) & 0xffff0000u);
}

// K1: L2-normalize rows of input_x; emit bf16 in MFMA fragment orders.
//   MFMA 16x16x32 bf16 (verified, learn_hip m89):
//     A: lane l, reg j -> A[l&15][(l>>4)*8 + j]
//     B: lane l, reg j -> B[(l>>4)*8 + j][l&15]
//     D: lane l, reg q -> D[(l>>4)*4 + q][l&15]
// xb1: B-frags for y = W @ xnT: K-dim = k, col = b.   [bt(4)][kstep(128)][lane] x short8
// xa2: A-frags for d^T = xa2 @ (NC*y^T): A[j][b] = xn[b][jcol]. [jt(256)][ks(2)][lane] x short8
__global__ __launch_bounds__(256) void k_norm(const float* __restrict__ x,
                                              unsigned short* __restrict__ xb1,
                                              unsigned short* __restrict__ xa2) {
    const int b = blockIdx.x;
    const int tid = threadIdx.x;
    const float* row = x + (size_t)b * DIM;

    float ss = 0.f;
    for (int k = tid * 4; k < DIM; k += 256 * 4) {
        float4 v = ld4(row + k);
        ss += v.x * v.x + v.y * v.y + v.z * v.z + v.w * v.w;
    }
#pragma unroll
    for (int m = 32; m >= 1; m >>= 1) ss += __shfl_xor(ss, m, 64);

    __shared__ float wsum[4];
    if ((tid & 63) == 0) wsum[tid >> 6] = ss;
    __syncthreads();
    const float total = wsum[0] + wsum[1] + wsum[2] + wsum[3];
    const float scale = 1.0f / (sqrtf(total) + 1e-8f);

    const int bt = b >> 4;            // xb1 b-tile
    const int li = b & 15;            // xb1 col-in-tile
    const int ks  = b >> 5;           // xa2 K-step (0/1)
    const int bhi = (b >> 3) & 3;     // xa2 lane-high bits
    const int br  = b & 7;            // xa2 reg index

    for (int k = tid; k < DIM; k += 256) {
        const float v = row[k] * scale;
        const unsigned short h = f2bf(v);
        const int l1 = li | (((k & 31) >> 3) << 4);
        xb1[(size_t)((((bt * 128) + (k >> 5)) * 64 + l1) << 3) + (k & 7)] = h;
        const int l2 = (k & 15) | (bhi << 4);
        xa2[(size_t)(((((k >> 4) * 2) + ks) * 64 + l2) << 3) + br] = h;
    }
}

// K2: ypart[kc] = W[rt*16 .. +16, kc*1024 .. +1024] @ xnT-chunk
// grid (256, 4) x 256 thr.
__global__ __launch_bounds__(256, 4) void k_wxt(const float* __restrict__ W,
                                                const unsigned short* __restrict__ xb1,
                                                float* __restrict__ ypart) {
    __shared__ f32x4 yp[4][4][64];   // [wave][bt][lane], 16 KB

    const int tid = threadIdx.x;
    const int w = tid >> 6;
    const int l = tid & 63;
    const int lr = l & 15;
    const int lh = l >> 4;
    const int rt = blockIdx.x;
    const int kc = blockIdx.y;
    const int i0 = rt * 16;

    float4 wa[8], wb[8];
    const float* wp0 = W + (size_t)(i0 + lr) * DIM + (kc * 32 + w * 8) * 32 + lh * 8;
#pragma unroll
    for (int s = 0; s < 8; ++s) {
        wa[s] = ld4(wp0 + s * 32);
        wb[s] = ld4(wp0 + s * 32 + 4);
    }

    f32x4 acc0 = {0.f, 0.f, 0.f, 0.f};
    f32x4 acc1 = acc0, acc2 = acc0, acc3 = acc0;
    const short8* xb1v = (const short8*)xb1;

#pragma unroll
    for (int s = 0; s < 8; ++s) {
        const int kbg = kc * 32 + w * 8 + s;
        const int bs = kbg * 64 + l;
        const short8 b0 = xb1v[bs];
        const short8 b1 = xb1v[bs + 8192];
        const short8 b2 = xb1v[bs + 16384];
        const short8 b3 = xb1v[bs + 24576];
        u32x4 ap;
        ap[0] = pack_bf2(wa[s].x, wa[s].y);
        ap[1] = pack_bf2(wa[s].z, wa[s].w);
        ap[2] = pack_bf2(wb[s].x, wb[s].y);
        ap[3] = pack_bf2(wb[s].z, wb[s].w);
        const short8 a = __builtin_bit_cast(short8, ap);
        acc0 = __builtin_amdgcn_mfma_f32_16x16x32_bf16(a, b0, acc0, 0, 0, 0);
        acc1 = __builtin_amdgcn_mfma_f32_16x16x32_bf16(a, b1, acc1, 0, 0, 0);
        acc2 = __builtin_amdgcn_mfma_f32_16x16x32_bf16(a, b2, acc2, 0, 0, 0);
        acc3 = __builtin_amdgcn_mfma_f32_16x16x32_bf16(a, b3, acc3, 0, 0, 0);
    }
    yp[w][0][l] = acc0;
    yp[w][1][l] = acc1;
    yp[w][2][l] = acc2;
    yp[w][3][l] = acc3;
    __syncthreads();

    {
        const int bb = tid & 63;
        const int btt = bb >> 4;
        const int rb = tid >> 6;
#pragma unroll
        for (int q = 0; q < 4; ++q) {
            const int r = rb * 4 + q;
            const int lii = (bb & 15) | ((r >> 2) << 4);
            const int jq = r & 3;
            float s = yp[0][btt][lii][jq] + yp[1][btt][lii][jq]
                    + yp[2][btt][lii][jq] + yp[3][btt][lii][jq];
            ypart[((size_t)kc * DIM + (i0 + r)) * 64 + bb] = s;
        }
    }
}

// K2b: reduce 4 K-partials; emit phase-2 B-fragments yab = bf16(NC * y^T)
__global__ __launch_bounds__(256) void k_yfrag(const float* __restrict__ ypart,
                                               unsigned short* __restrict__ yab) {
    const int gid = blockIdx.x * 256 + threadIdx.x;   // 0 .. 16383
    const int rt = gid >> 6;
    const int l = gid & 63;
    const int lr = l & 15;
    const int lh = l >> 4;
    const float NC = -0.01f / 64.0f;
    short8* yabv = (short8*)yab;

#pragma unroll
    for (int h = 0; h < 2; ++h) {
        float s[8] = {};
#pragma unroll
        for (int kc = 0; kc < 4; ++kc) {
            const float* p = ypart + ((size_t)kc * DIM + (rt * 16 + lr)) * 64 + h * 32 + lh * 8;
            const float4 f0 = ld4(p);
            const float4 f1 = ld4(p + 4);
            s[0] += f0.x; s[1] += f0.y; s[2] += f0.z; s[3] += f0.w;
            s[4] += f1.x; s[5] += f1.y; s[6] += f1.z; s[7] += f1.w;
        }
        short8 fr;
#pragma unroll
        for (int j = 0; j < 8; ++j) fr[j] = (short)f2bf(NC * s[j]);
        yabv[(size_t)(rt * 64 + l) * 2 + h] = fr;
    }
}

// K3: out = W - lr*G + d. Wave owns one jt column-strip (a-frags loop-invariant)
// and streams 8 row-tiles: per iter {yab frag (L2), W, G} + 2 MFMA + store.
// 2048 blocks x 256 thr @ 8 waves/SIMD -> max TLP.
__global__ __launch_bounds__(256, 8) void k_update(const float* __restrict__ W,
                                                   const float* __restrict__ G,
                                                   const unsigned short* __restrict__ xa2,
                                                   const unsigned short* __restrict__ yab,
                                                   float* __restrict__ out) {
    const int tid = threadIdx.x;
    const int wv = tid >> 6;
    const int l = tid & 63;
    const int lr = l & 15;
    const int lh = l >> 4;

    const int wgid = blockIdx.x * 4 + wv;    // 0 .. 8191
    const int jt = wgid >> 5;                // 0 .. 255 (column tile, 16 cols)
    const int rc = wgid & 31;                // 0 .. 31  (row chunk, 8 row-tiles)

    const short8* xa2v = (const short8*)xa2;
    const short8* yabv = (const short8*)yab;

    // loop-invariant A-fragments for this column strip
    const short8 a0 = xa2v[(size_t)(jt * 2 + 0) * 64 + l];
    const short8 a1 = xa2v[(size_t)(jt * 2 + 1) * 64 + l];

    constexpr float LRc = 0.001f;
    const int colb = jt * 16 + lh * 4;

#pragma unroll
    for (int r8 = 0; r8 < 8; ++r8) {
        const int rt = rc * 8 + r8;
        const short8 ya0 = yabv[(size_t)(rt * 64 + l) * 2];
        const short8 ya1 = yabv[(size_t)(rt * 64 + l) * 2 + 1];
        const size_t idx = (size_t)(rt * 16 + lr) * DIM + colb;
        const float4 w4 = ld4(W + idx);
        const float4 g4 = ld4(G + idx);
        f32x4 d = {0.f, 0.f, 0.f, 0.f};
        d = __builtin_amdgcn_mfma_f32_16x16x32_bf16(a0, ya0, d, 0, 0, 0);
        d = __builtin_amdgcn_mfma_f32_16x16x32_bf16(a1, ya1, d, 0, 0, 0);
        float4 o;
        o.x = w4.x - LRc * g4.x + d[0];
        o.y = w4.y - LRc * g4.y + d[1];
        o.z = w4.z - LRc * g4.z + d[2];
        o.w = w4.w - LRc * g4.w + d[3];
        *reinterpret_cast<float4*>(out + idx) = o;
    }
}

extern "C" void kernel_launch(void* const* d_in, const int* in_sizes, int n_in,
                              void* d_out, int out_size, void* d_ws, size_t ws_size,
                              hipStream_t stream) {
    const float* W = (const float*)d_in[0];   // weight  (DIM x DIM)
    const float* X = (const float*)d_in[1];   // input_x (BATCH x DIM)
    const float* G = (const float*)d_in[2];   // grad    (DIM x DIM)
    float* out = (float*)d_out;

    unsigned short* xb1 = (unsigned short*)d_ws;                    // 512 KB
    unsigned short* xa2 = xb1 + (size_t)DIM * BATCH;                // 512 KB
    unsigned short* yab = xa2 + (size_t)DIM * BATCH;                // 512 KB
    float* ypart = (float*)(yab + (size_t)DIM * BATCH);             // 4 MB

    hipLaunchKernelGGL(k_norm, dim3(BATCH), dim3(256), 0, stream, X, xb1, xa2);
    hipLaunchKernelGGL(k_wxt, dim3(256, 4), dim3(256), 0, stream, W, xb1, ypart);
    hipLaunchKernelGGL(k_yfrag, dim3(64), dim3(256), 0, stream, ypart, yab);
    hipLaunchKernelGGL(k_update, dim3(2048), dim3(256), 0, stream,
                       W, G, xa2, yab, out);
}

// Round 8
// 65.479 us; speedup vs baseline: 1.2707x; 1.1219x over previous
//
#include <hip/hip_runtime.h>
#include <math.h>

#define DIM 4096
#define BATCH 64

typedef __attribute__((ext_vector_type(8))) short short8;
typedef __attribute__((ext_vector_type(4))) float f32x4;
typedef __attribute__((ext_vector_type(4))) unsigned int u32x4;

__device__ __forceinline__ float4 ld4(const float* p) {
    return *reinterpret_cast<const float4*>(p);
}

// f32 -> bf16 bits, round-to-nearest-even
__device__ __forceinline__ unsigned short f2bf(float f) {
    unsigned u = __builtin_bit_cast(unsigned, f);
    u = (u + 0x7fffu + ((u >> 16) & 1u)) >> 16;
    return (unsigned short)u;
}

// pack two f32 -> one u32 of two bf16 (truncation; cheap)
__device__ __forceinline__ unsigned pack_bf2(float x, float y) {
    return (__builtin_bit_cast(unsigned, x) >> 16) |
           (__builtin_bit_cast(unsigned, y) & 0xffff0000u);
}

// K1: L2-normalize rows of input_x; emit bf16 in MFMA B-fragment order.
//   B-frag: lane l, reg j -> B[(l>>4)*8 + j][l&15]
// xb1: B for phase 1 (y = W @ xnT), K-dim = k, col = b. [bt4][kstep128][lane]xshort8
// xb2: B for phase 2 (d = (NC*y) @ xn), K-dim = b, col = j. [jt256][ks2][lane]xshort8
__global__ __launch_bounds__(256) void k_norm(const float* __restrict__ x,
                                              unsigned short* __restrict__ xb1,
                                              unsigned short* __restrict__ xb2) {
    const int b = blockIdx.x;
    const int tid = threadIdx.x;
    const float* row = x + (size_t)b * DIM;

    float ss = 0.f;
    for (int k = tid * 4; k < DIM; k += 256 * 4) {
        float4 v = ld4(row + k);
        ss += v.x * v.x + v.y * v.y + v.z * v.z + v.w * v.w;
    }
#pragma unroll
    for (int m = 32; m >= 1; m >>= 1) ss += __shfl_xor(ss, m, 64);

    __shared__ float wsum[4];
    if ((tid & 63) == 0) wsum[tid >> 6] = ss;
    __syncthreads();
    const float total = wsum[0] + wsum[1] + wsum[2] + wsum[3];
    const float scale = 1.0f / (sqrtf(total) + 1e-8f);

    const int bt = b >> 4;            // xb1 b-tile
    const int li = b & 15;            // xb1 col-in-tile
    const int ks = b >> 5;            // xb2 K-step (0/1)
    const int hi = (b & 31) >> 3;     // xb2 lane-high bits
    const int jr = b & 7;             // xb2 reg index

    for (int k = tid; k < DIM; k += 256) {
        const float v = row[k] * scale;
        const unsigned short h = f2bf(v);
        const int l1 = li | (((k & 31) >> 3) << 4);
        xb1[(size_t)((((bt * 128) + (k >> 5)) * 64 + l1) << 3) + (k & 7)] = h;
        const int l2 = (k & 15) | (hi << 4);
        xb2[(size_t)(((((k >> 4) * 2) + ks) * 64 + l2) << 3) + jr] = h;
    }
}

// Fused: 512 blocks; twin blocks (same rt, half=0/1) share phase-1 work
// (redundant compute, L2-shared W reads on the same XCD) and split phase-2
// columns. 70 KB LDS -> 2 blocks/CU -> phases of co-resident blocks stagger.
__global__ __launch_bounds__(1024, 8) void k_fused(const float* __restrict__ W,
                                                   const float* __restrict__ G,
                                                   const unsigned short* __restrict__ xb1,
                                                   const unsigned short* __restrict__ xb2,
                                                   float* __restrict__ out) {
    // LDS lifetimes (barrier-separated):
    //   yp  = lds[0 .. 16384)        phase-1 per-wave partial D-tiles (64 KB)
    //   y2  = lds[16384 .. 17472)    reduced y[16][68-padded]
    //   dl  = lds[wv*1088 .. +1088)  phase-2 wave-private transpose (16x68)
    __shared__ __align__(16) float lds[17472];
    float* yp = lds;
    float* y2 = lds + 16384;

    const int tid = threadIdx.x;
    const int wv = tid >> 6;      // wave 0..15
    const int l  = tid & 63;      // lane
    const int lr = l & 15;
    const int lh = l >> 4;

    // XCD-aware swizzle; twins (rt, half) land on the same XCD, bids 8 apart.
    const int bid = blockIdx.x;                 // 0..511
    const int sid = (bid & 7) * 64 + (bid >> 3);
    const int rt  = sid >> 1;                   // 0..255 row tile
    const int half = sid & 1;                   // phase-2 column half
    const int i0 = rt * 16;

    // ---------------- phase 1: y = W_rows @ xnT, wave wv covers K [wv*256, +256)
    f32x4 acc0 = {0.f, 0.f, 0.f, 0.f};
    f32x4 acc1 = acc0, acc2 = acc0, acc3 = acc0;
    const short8* xb1v = (const short8*)xb1;

#pragma unroll 2
    for (int s = 0; s < 8; ++s) {
        const int kbg = wv * 8 + s;
        const float* wp = W + (size_t)(i0 + lr) * DIM + kbg * 32 + lh * 8;
        const float4 wa = ld4(wp);
        const float4 wb = ld4(wp + 4);
        const int bs = kbg * 64 + l;
        const short8 b0 = xb1v[bs];
        const short8 b1 = xb1v[bs + 8192];
        const short8 b2 = xb1v[bs + 16384];
        const short8 b3 = xb1v[bs + 24576];
        u32x4 ap;
        ap[0] = pack_bf2(wa.x, wa.y);
        ap[1] = pack_bf2(wa.z, wa.w);
        ap[2] = pack_bf2(wb.x, wb.y);
        ap[3] = pack_bf2(wb.z, wb.w);
        const short8 a = __builtin_bit_cast(short8, ap);
        acc0 = __builtin_amdgcn_mfma_f32_16x16x32_bf16(a, b0, acc0, 0, 0, 0);
        acc1 = __builtin_amdgcn_mfma_f32_16x16x32_bf16(a, b1, acc1, 0, 0, 0);
        acc2 = __builtin_amdgcn_mfma_f32_16x16x32_bf16(a, b2, acc2, 0, 0, 0);
        acc3 = __builtin_amdgcn_mfma_f32_16x16x32_bf16(a, b3, acc3, 0, 0, 0);
    }
    {
        f32x4* dst = (f32x4*)yp;
        dst[(wv * 4 + 0) * 64 + l] = acc0;
        dst[(wv * 4 + 1) * 64 + l] = acc1;
        dst[(wv * 4 + 2) * 64 + l] = acc2;
        dst[(wv * 4 + 3) * 64 + l] = acc3;
    }
    __syncthreads();

    // reduce 16 partials: thread t owns y element (r = t>>6, b = t&63)
    {
        const int r  = tid >> 6;
        const int bb = tid & 63;
        const int btt = bb >> 4;
        const int lii = (bb & 15) | ((r >> 2) << 4);
        const int jq  = r & 3;
        float s = 0.f;
#pragma unroll
        for (int w = 0; w < 16; ++w) s += yp[(((w * 4 + btt) * 64 + lii) << 2) + jq];
        y2[r * 68 + bb] = s;
    }
    __syncthreads();

    // phase-2 A-fragments: ya = (-alpha/B) * y, bf16
    const float NC = -0.01f / 64.0f;
    short8 ya0, ya1;
#pragma unroll
    for (int j = 0; j < 8; ++j) {
        ya0[j] = (short)f2bf(NC * y2[lr * 68 + lh * 8 + j]);
        ya1[j] = (short)f2bf(NC * y2[lr * 68 + 32 + lh * 8 + j]);
    }
    __syncthreads();   // protect yp/y2 before dl overwrites them

    // ---------------- phase 2: wave owns cols [half*2048 + wv*128, +128),
    // as 2 chunks of 64 cols (4 jt tiles each). dl is wave-private: no barriers.
    constexpr float LRc = 0.001f;
    const short8* xb2v = (const short8*)xb2;
    float* dl = lds + wv * 1088;       // 16 x 68 f32
    const int colbase = half * 2048 + wv * 128;
    const int cc4 = (l & 15) * 4;      // col-in-chunk (f32 index)
    const int rr0 = l >> 4;            // row group 0..3

    for (int c = 0; c < 2; ++c) {
        const int col0 = colbase + c * 64;
        const int jt0 = col0 >> 4;
        // 4 jt tiles of d = ya @ xb2  (8 MFMA)
        f32x4 dt[4];
#pragma unroll
        for (int tl = 0; tl < 4; ++tl) {
            const int bslot = (jt0 + tl) * 128 + l;
            f32x4 d = {0.f, 0.f, 0.f, 0.f};
            d = __builtin_amdgcn_mfma_f32_16x16x32_bf16(ya0, xb2v[bslot], d, 0, 0, 0);
            d = __builtin_amdgcn_mfma_f32_16x16x32_bf16(ya1, xb2v[bslot + 64], d, 0, 0, 0);
            dt[tl] = d;
        }
        // transpose through wave-private LDS (write: 2-way alias = free)
#pragma unroll
        for (int tl = 0; tl < 4; ++tl)
#pragma unroll
            for (int q = 0; q < 4; ++q)
                dl[(lh * 4 + q) * 68 + tl * 16 + lr] = dt[tl][q];

        // coalesced epilogue: per instr 4 rows x 256B contiguous
        float4 w4[4], g4[4];
#pragma unroll
        for (int i = 0; i < 4; ++i) {
            const size_t gidx = (size_t)(i0 + rr0 + 4 * i) * DIM + col0 + cc4;
            w4[i] = ld4(W + gidx);
            g4[i] = ld4(G + gidx);
        }
#pragma unroll
        for (int i = 0; i < 4; ++i) {
            const float4 dd = ld4(dl + (rr0 + 4 * i) * 68 + cc4);
            const size_t gidx = (size_t)(i0 + rr0 + 4 * i) * DIM + col0 + cc4;
            float4 o;
            o.x = w4[i].x - LRc * g4[i].x + dd.x;
            o.y = w4[i].y - LRc * g4[i].y + dd.y;
            o.z = w4[i].z - LRc * g4[i].z + dd.z;
            o.w = w4[i].w - LRc * g4[i].w + dd.w;
            *reinterpret_cast<float4*>(out + gidx) = o;
        }
    }
}

extern "C" void kernel_launch(void* const* d_in, const int* in_sizes, int n_in,
                              void* d_out, int out_size, void* d_ws, size_t ws_size,
                              hipStream_t stream) {
    const float* W = (const float*)d_in[0];   // weight  (DIM x DIM)
    const float* X = (const float*)d_in[1];   // input_x (BATCH x DIM)
    const float* G = (const float*)d_in[2];   // grad    (DIM x DIM)
    float* out = (float*)d_out;

    unsigned short* xb1 = (unsigned short*)d_ws;               // 512 KB
    unsigned short* xb2 = xb1 + (size_t)DIM * BATCH;           // 512 KB

    hipLaunchKernelGGL(k_norm, dim3(BATCH), dim3(256), 0, stream, X, xb1, xb2);
    hipLaunchKernelGGL(k_fused, dim3(512), dim3(1024), 0, stream,
                       W, G, xb1, xb2, out);
}